// Round 2
// baseline (458.002 us; speedup 1.0000x reference)
//
#include <hip/hip_runtime.h>
#include <stdint.h>

typedef unsigned short u16;

#define S_ 4096
#define B_ 8
#define H_ 1024
#define F_ 1024
#define M_ (S_ * B_)   // 32768
#define N_ F_          // 1024
#define K_ H_          // 1024

#define BM 256
#define BN 256
#define BK 64
#define NT (K_ / BK)   // 16 K-tiles

typedef short short8 __attribute__((ext_vector_type(8)));
typedef float floatx4 __attribute__((ext_vector_type(4)));

// RNE float -> bf16 bits (values are well-behaved: no NaN/Inf in this problem)
__device__ __forceinline__ u16 f2bf(float f) {
    union { float f; uint32_t u; } c;
    c.f = f;
    uint32_t u = c.u;
    uint32_t r = (u + 0x7fffu + ((u >> 16) & 1u)) >> 16;
    return (u16)r;
}

// async 16B/lane global -> LDS (dest = wave-uniform base + lane*16)
__device__ __forceinline__ void async_load16(const void* gptr, void* lptr) {
    __builtin_amdgcn_global_load_lds(
        (const __attribute__((address_space(1))) uint32_t*)gptr,
        (__attribute__((address_space(3))) uint32_t*)lptr,
        16 /*size*/, 0 /*offset*/, 0 /*aux*/);
}

// ---------------------------------------------------------------------------
// Kernel 1: transpose + cast W (K_ x N_ fp32, row-major) -> Bt (N_ x K_ bf16)
// (unchanged, verified)
// ---------------------------------------------------------------------------
__global__ __launch_bounds__(256) void transpose_cast_kernel(
    const float* __restrict__ w, u16* __restrict__ bt)
{
    __shared__ float tile[32][33];
    const int tx = threadIdx.x;  // 0..31
    const int ty = threadIdx.y;  // 0..7
    const int n0 = blockIdx.x * 32;
    const int k0 = blockIdx.y * 32;
#pragma unroll
    for (int j = 0; j < 4; ++j)
        tile[ty + j * 8][tx] = w[(size_t)(k0 + ty + j * 8) * N_ + n0 + tx];
    __syncthreads();
#pragma unroll
    for (int j = 0; j < 4; ++j)
        bt[(size_t)(n0 + ty + j * 8) * K_ + k0 + tx] =
            f2bf(tile[tx][ty + j * 8]);
}

// ---------------------------------------------------------------------------
// Kernel 2: LayerNorm, one WAVE per row (64 lanes x 16 floats = 1024).
// UNCHANGED from r1 so the round delta attributes to the GEMM.
// ---------------------------------------------------------------------------
#define LN_BLOCKS 2048
__global__ __launch_bounds__(256) void ln_kernel(
    const float* __restrict__ x, const float* __restrict__ scale,
    const float* __restrict__ bias, float* __restrict__ ln_out,
    u16* __restrict__ ln_bf16)
{
    const int lane = threadIdx.x & 63;
    const int wid  = (blockIdx.x << 2) | (threadIdx.x >> 6);  // global wave id
    const int nwaves = LN_BLOCKS * 4;                          // 8192

    float4 sc[4], bi[4];
#pragma unroll
    for (int j = 0; j < 4; ++j) {
        sc[j] = reinterpret_cast<const float4*>(scale)[j * 64 + lane];
        bi[j] = reinterpret_cast<const float4*>(bias)[j * 64 + lane];
    }

    for (int row = wid; row < M_; row += nwaves) {
        const float4* xr = reinterpret_cast<const float4*>(x + (size_t)row * H_);
        float4 v[4];
        float s = 0.f, sq = 0.f;
#pragma unroll
        for (int j = 0; j < 4; ++j) {
            v[j] = xr[j * 64 + lane];
            s  += v[j].x + v[j].y + v[j].z + v[j].w;
            sq += v[j].x * v[j].x + v[j].y * v[j].y +
                  v[j].z * v[j].z + v[j].w * v[j].w;
        }
#pragma unroll
        for (int off = 32; off >= 1; off >>= 1) {
            s  += __shfl_xor(s, off, 64);
            sq += __shfl_xor(sq, off, 64);
        }
        const float mu   = s * (1.0f / H_);
        const float var  = sq * (1.0f / H_) - mu * mu;
        const float rstd = rsqrtf(var + 1e-6f);

        float4* yr = reinterpret_cast<float4*>(ln_out + (size_t)row * H_);
        ushort4* hr = reinterpret_cast<ushort4*>(ln_bf16 + (size_t)row * H_);
#pragma unroll
        for (int j = 0; j < 4; ++j) {
            float4 y;
            y.x = (v[j].x - mu) * rstd * sc[j].x + bi[j].x;
            y.y = (v[j].y - mu) * rstd * sc[j].y + bi[j].y;
            y.z = (v[j].z - mu) * rstd * sc[j].z + bi[j].z;
            y.w = (v[j].w - mu) * rstd * sc[j].w + bi[j].w;
            yr[j * 64 + lane] = y;
            ushort4 h;
            h.x = f2bf(y.x); h.y = f2bf(y.y); h.z = f2bf(y.z); h.w = f2bf(y.w);
            hr[j * 64 + lane] = h;
        }
    }
}

// ---------------------------------------------------------------------------
// Kernel 3: GEMM C = A * Bt^T, 256x256 tile, BK=64, 8 waves (2M x 4N),
// 8-phase schedule (T3+T4+T5): 4 phases per K-tile, each
//   { ds_read subtile + 2 quarter-stage global_load_lds ; s_barrier ;
//     setprio(1) 16 MFMA setprio(0) ; s_barrier }
// Counted vmcnt(1) at the K-tile boundary only — never a full drain in-loop.
//
// Staging prefetch schedule (quarter = 64 rows of A or B; c = t&1 live buf):
//   tile t+1, buf c^1 (idle):  A-Q1@p0, A-Q3@p1, B-Q0@p0, B-Q1@p1, B-Q2@p2,
//                              B-Q3@p3
//   tile t+2, buf c (LIVE):    A-Q0@p2, A-Q2@p3
// Race-freedom of the live-buffer stages: A-Q0 rows (0-63) are last read at
// phase 1 (wm=0 reads rows 32p..32p+31; wm=1 reads 128+32p..159+32p), sealed
// by the phase-1 end barrier; A-Q2 rows (128-191) likewise (wm=1 p0/p1).
// Boundary wait: newest in-flight op is A-Q2(t+2); vmcnt(1) retires
// everything tile t+1 needs (vmcnt is a FIFO counter; VM ops retire in order).
//
// Addressing (XOR chunk swizzle, staging pattern, epilogue) is byte-identical
// to the refcheck-verified r1 kernel — only the sync structure changed.
// ---------------------------------------------------------------------------
__global__ __launch_bounds__(512, 2) void gemm_bt_kernel(
    const u16* __restrict__ A, const u16* __restrict__ Bt,
    float* __restrict__ C)
{
    __shared__ __align__(16) u16 As[2][BM * BK];   // 2 x 32 KiB
    __shared__ __align__(16) u16 Bs[2][BN * BK];   // 2 x 32 KiB

    const int tid  = threadIdx.x;
    const int wid  = tid >> 6;        // 0..7
    const int lane = tid & 63;
    const int wm   = wid >> 2;        // 0..1  (M half)
    const int wn   = wid & 3;         // 0..3  (N quarter)

    const int bid  = blockIdx.x;
    const int bx   = (bid >> 3) & 3;
    const int by   = ((bid >> 5) << 3) | (bid & 7);
    const int row0 = by * BM;
    const int col0 = bx * BN;

    floatx4 acc[8][4];
#pragma unroll
    for (int i = 0; i < 8; ++i)
#pragma unroll
        for (int j = 0; j < 4; ++j) acc[i][j] = (floatx4)0.0f;

    // staging: one async_load16 per wave covers 8 rows (64 lanes * 16B);
    // quarter i = rows [i*64, i*64+64). lane (r=lane>>3, c=lane&7) fetches
    // global chunk (c ^ r) of its row (XOR swizzle via global address).
    const int srow   = (wid << 3) | (lane >> 3);
    const int schunk = (lane & 7) ^ (srow & 7);
    const u16* Ag = A  + (size_t)(row0 + srow) * K_ + schunk * 8;
    const u16* Bg = Bt + (size_t)(col0 + srow) * K_ + schunk * 8;

#define QSA(buf, kt, i)                                                       \
    async_load16(Ag + (size_t)((i) * 64) * K_ + (size_t)(kt) * BK,            \
                 (char*)As[buf] + (size_t)((i) * 64 + (wid << 3)) * 128)
#define QSB(buf, kt, i)                                                       \
    async_load16(Bg + (size_t)((i) * 64) * K_ + (size_t)(kt) * BK,            \
                 (char*)Bs[buf] + (size_t)((i) * 64 + (wid << 3)) * 128)
#define BARRIER() asm volatile("s_barrier" ::: "memory")

#define LOADA(mp_)                                                            \
    do {                                                                      \
        _Pragma("unroll")                                                     \
        for (int mi = 0; mi < 2; ++mi)                                        \
            _Pragma("unroll")                                                 \
            for (int ks = 0; ks < 2; ++ks) {                                  \
                const int mt = (mp_) * 2 + mi;                                \
                const int r  = (wm << 7) | (mt << 4) | (lane & 15);           \
                const int q  = (ks << 2) | (lane >> 4);                       \
                const int cc = q ^ (r & 7);                                   \
                af[mi][ks] = *reinterpret_cast<const short8*>(                \
                    (const char*)As[c] + (size_t)r * 128 + cc * 16);          \
            }                                                                 \
    } while (0)

#define MFMA8(mp_)                                                            \
    do {                                                                      \
        __builtin_amdgcn_s_setprio(1);                                        \
        _Pragma("unroll")                                                     \
        for (int mi = 0; mi < 2; ++mi)                                        \
            _Pragma("unroll")                                                 \
            for (int nt = 0; nt < 4; ++nt)                                    \
                _Pragma("unroll")                                             \
                for (int ks = 0; ks < 2; ++ks)                                \
                    acc[(mp_) * 2 + mi][nt] =                                 \
                        __builtin_amdgcn_mfma_f32_16x16x32_bf16(              \
                            af[mi][ks], bfrag[nt][ks],                        \
                            acc[(mp_) * 2 + mi][nt], 0, 0, 0);                \
        __builtin_amdgcn_s_setprio(0);                                        \
    } while (0)

    // prologue: full tile 0 into buf0; early A-Q0/A-Q2 of tile 1 into buf1.
    // vmcnt(2) retires exactly tile 0's 8 loads (the 2 newest are tile 1's).
#pragma unroll
    for (int i = 0; i < 4; ++i) { QSA(0, 0, i); QSB(0, 0, i); }
    QSA(1, 1, 0);
    QSA(1, 1, 2);
    asm volatile("s_waitcnt vmcnt(2)" ::: "memory");
    BARRIER();

    for (int t = 0; t < NT; ++t) {
        const int c = t & 1;
        short8 bfrag[4][2];
        short8 af[2][2];

        // ---- phase 0: all B frags + A frags mt0,1 ----
#pragma unroll
        for (int nt = 0; nt < 4; ++nt)
#pragma unroll
            for (int ks = 0; ks < 2; ++ks) {
                const int r  = (wn << 6) | (nt << 4) | (lane & 15);
                const int q  = (ks << 2) | (lane >> 4);
                const int cc = q ^ (r & 7);
                bfrag[nt][ks] = *reinterpret_cast<const short8*>(
                    (const char*)Bs[c] + (size_t)r * 128 + cc * 16);
            }
        LOADA(0);
        if (t + 1 < NT) { QSA(c ^ 1, t + 1, 1); QSB(c ^ 1, t + 1, 0); }
        BARRIER();
        MFMA8(0);
        BARRIER();

        // ---- phase 1 ----
        LOADA(1);
        if (t + 1 < NT) { QSA(c ^ 1, t + 1, 3); QSB(c ^ 1, t + 1, 1); }
        BARRIER();
        MFMA8(1);
        BARRIER();

        // ---- phase 2 (A-Q0 of t+2 into LIVE buf: rows 0-63, sealed @p1) ----
        LOADA(2);
        if (t + 1 < NT) QSB(c ^ 1, t + 1, 2);
        if (t + 2 < NT) QSA(c, t + 2, 0);
        BARRIER();
        MFMA8(2);
        BARRIER();

        // ---- phase 3 (A-Q2 of t+2: rows 128-191, sealed @p1) ----
        LOADA(3);
        if (t + 1 < NT) QSB(c ^ 1, t + 1, 3);
        if (t + 2 < NT) QSA(c, t + 2, 2);
        BARRIER();
        MFMA8(3);
        if (t + 1 < NT) {
            if (t + 2 < NT) asm volatile("s_waitcnt vmcnt(1)" ::: "memory");
            else            asm volatile("s_waitcnt vmcnt(0)" ::: "memory");
            BARRIER();
        }
    }
#undef QSA
#undef QSB
#undef BARRIER
#undef LOADA
#undef MFMA8

    // epilogue: C/D layout col = lane&15, row = (lane>>4)*4 + reg
#pragma unroll
    for (int mt = 0; mt < 8; ++mt) {
#pragma unroll
        for (int nt = 0; nt < 4; ++nt) {
            const int r0 = row0 + (wm << 7) + (mt << 4) + ((lane >> 4) << 2);
            const int c  = col0 + (wn << 6) + (nt << 4) + (lane & 15);
#pragma unroll
            for (int r = 0; r < 4; ++r)
                C[(size_t)(r0 + r) * N_ + c] = acc[mt][nt][r];
        }
    }
}

// ---------------------------------------------------------------------------
extern "C" void kernel_launch(void* const* d_in, const int* in_sizes, int n_in,
                              void* d_out, int out_size, void* d_ws, size_t ws_size,
                              hipStream_t stream) {
    const float* x      = (const float*)d_in[0];   // (S,B,H)
    const float* scale  = (const float*)d_in[1];   // (H,)
    const float* lnbias = (const float*)d_in[2];   // (H,)
    const float* weight = (const float*)d_in[3];   // (H,F)

    float* out    = (float*)d_out;                     // (S,B,F)
    float* ln_out = (float*)d_out + (size_t)M_ * N_;   // (S,B,H)

    // workspace: [A bf16: M_*K_ u16 = 64 MiB][Bt bf16: N_*K_ u16 = 2 MiB]
    u16* ln_bf16 = (u16*)d_ws;
    u16* bt      = (u16*)d_ws + (size_t)M_ * K_;

    transpose_cast_kernel<<<dim3(N_ / 32, K_ / 32), dim3(32, 8), 0, stream>>>(
        weight, bt);
    ln_kernel<<<LN_BLOCKS, 256, 0, stream>>>(x, scale, lnbias, ln_out, ln_bf16);
    gemm_bt_kernel<<<(M_ / BM) * (N_ / BN), 512, 0, stream>>>(ln_bf16, bt, out);
}

// Round 3
// 445.638 us; speedup vs baseline: 1.0277x; 1.0277x over previous
//
#include <hip/hip_runtime.h>
#include <stdint.h>

typedef unsigned short u16;

#define S_ 4096
#define B_ 8
#define H_ 1024
#define F_ 1024
#define M_ (S_ * B_)   // 32768
#define N_ F_          // 1024
#define K_ H_          // 1024

#define BM 128
#define BN 128
#define BK 64

typedef short short8 __attribute__((ext_vector_type(8)));
typedef float floatx4 __attribute__((ext_vector_type(4)));

// RNE float -> bf16 bits (values are well-behaved: no NaN/Inf in this problem)
__device__ __forceinline__ u16 f2bf(float f) {
    union { float f; uint32_t u; } c;
    c.f = f;
    uint32_t u = c.u;
    uint32_t r = (u + 0x7fffu + ((u >> 16) & 1u)) >> 16;
    return (u16)r;
}

// async 16B/lane global -> LDS (dest = wave-uniform base + lane*16)
__device__ __forceinline__ void async_load16(const void* gptr, void* lptr) {
    __builtin_amdgcn_global_load_lds(
        (const __attribute__((address_space(1))) uint32_t*)gptr,
        (__attribute__((address_space(3))) uint32_t*)lptr,
        16 /*size*/, 0 /*offset*/, 0 /*aux*/);
}

// ---------------------------------------------------------------------------
// Kernel 1: transpose + cast W (K_ x N_ fp32, row-major) -> Bt (N_ x K_ bf16)
// (unchanged, verified)
// ---------------------------------------------------------------------------
__global__ __launch_bounds__(256) void transpose_cast_kernel(
    const float* __restrict__ w, u16* __restrict__ bt)
{
    __shared__ float tile[32][33];
    const int tx = threadIdx.x;  // 0..31
    const int ty = threadIdx.y;  // 0..7
    const int n0 = blockIdx.x * 32;
    const int k0 = blockIdx.y * 32;
#pragma unroll
    for (int j = 0; j < 4; ++j)
        tile[ty + j * 8][tx] = w[(size_t)(k0 + ty + j * 8) * N_ + n0 + tx];
    __syncthreads();
#pragma unroll
    for (int j = 0; j < 4; ++j)
        bt[(size_t)(n0 + ty + j * 8) * K_ + k0 + tx] =
            f2bf(tile[tx][ty + j * 8]);
}

// ---------------------------------------------------------------------------
// Kernel 2: LayerNorm, one WAVE per row (64 lanes x 16 floats = 1024).
// r1 version, kept: grid-stride 2048 blocks, hoisted scale/bias, no LDS.
// ---------------------------------------------------------------------------
#define LN_BLOCKS 2048
__global__ __launch_bounds__(256) void ln_kernel(
    const float* __restrict__ x, const float* __restrict__ scale,
    const float* __restrict__ bias, float* __restrict__ ln_out,
    u16* __restrict__ ln_bf16)
{
    const int lane = threadIdx.x & 63;
    const int wid  = (blockIdx.x << 2) | (threadIdx.x >> 6);  // global wave id
    const int nwaves = LN_BLOCKS * 4;                          // 8192

    float4 sc[4], bi[4];
#pragma unroll
    for (int j = 0; j < 4; ++j) {
        sc[j] = reinterpret_cast<const float4*>(scale)[j * 64 + lane];
        bi[j] = reinterpret_cast<const float4*>(bias)[j * 64 + lane];
    }

    for (int row = wid; row < M_; row += nwaves) {
        const float4* xr = reinterpret_cast<const float4*>(x + (size_t)row * H_);
        float4 v[4];
        float s = 0.f, sq = 0.f;
#pragma unroll
        for (int j = 0; j < 4; ++j) {
            v[j] = xr[j * 64 + lane];
            s  += v[j].x + v[j].y + v[j].z + v[j].w;
            sq += v[j].x * v[j].x + v[j].y * v[j].y +
                  v[j].z * v[j].z + v[j].w * v[j].w;
        }
#pragma unroll
        for (int off = 32; off >= 1; off >>= 1) {
            s  += __shfl_xor(s, off, 64);
            sq += __shfl_xor(sq, off, 64);
        }
        const float mu   = s * (1.0f / H_);
        const float var  = sq * (1.0f / H_) - mu * mu;
        const float rstd = rsqrtf(var + 1e-6f);

        float4* yr = reinterpret_cast<float4*>(ln_out + (size_t)row * H_);
        ushort4* hr = reinterpret_cast<ushort4*>(ln_bf16 + (size_t)row * H_);
#pragma unroll
        for (int j = 0; j < 4; ++j) {
            float4 y;
            y.x = (v[j].x - mu) * rstd * sc[j].x + bi[j].x;
            y.y = (v[j].y - mu) * rstd * sc[j].y + bi[j].y;
            y.z = (v[j].z - mu) * rstd * sc[j].z + bi[j].z;
            y.w = (v[j].w - mu) * rstd * sc[j].w + bi[j].w;
            yr[j * 64 + lane] = y;
            ushort4 h;
            h.x = f2bf(y.x); h.y = f2bf(y.y); h.z = f2bf(y.z); h.w = f2bf(y.w);
            hr[j * 64 + lane] = h;
        }
    }
}

// ---------------------------------------------------------------------------
// Kernel 3: GEMM C = A * Bt^T — EXACT r0 revert (best-measured: 429 µs total).
// 128x128 block tile, BK=64, 4 waves 2x2, 64x64/wave via 4x4
// mfma_f32_16x16x32_bf16, global_load_lds 16B staging, 32 KiB LDS
// -> ~3 blocks/CU; inter-block overlap forgives the barrier drain (m114).
// XOR chunk swizzle via pre-swizzled global source; XCD-swizzled 1-D grid.
// ---------------------------------------------------------------------------
__global__ __launch_bounds__(256) void gemm_bt_kernel(
    const u16* __restrict__ A, const u16* __restrict__ Bt,
    float* __restrict__ C)
{
    __shared__ __align__(16) u16 As[BM * BK];
    __shared__ __align__(16) u16 Bs[BN * BK];

    const int tid  = threadIdx.x;
    const int wave = tid >> 6;
    const int lane = tid & 63;
    const int wm   = wave >> 1;  // 0..1
    const int wn   = wave & 1;   // 0..1

    // XCD swizzle: by = (bid>>6)*8 + (bid&7), bx = (bid>>3)&7
    const int bid  = blockIdx.x;
    const int bx   = (bid >> 3) & 7;
    const int by   = ((bid >> 6) << 3) | (bid & 7);
    const int row0 = by * BM;
    const int col0 = bx * BN;

    floatx4 acc[4][4];
#pragma unroll
    for (int i = 0; i < 4; ++i)
#pragma unroll
        for (int j = 0; j < 4; ++j) acc[i][j] = (floatx4)0.0f;

    // staging: per call each wave fills 8 rows (64 lanes * 16B = 8 rows * 128B)
    // lane (r=lane>>3, c=lane&7) fetches global chunk (c ^ r) of row r
    const int srow = wave * 8 + (lane >> 3);             // row within 32-row group
    const int scol = (((lane & 7) ^ (lane >> 3)) * 8);   // swizzled bf16 col
    const u16* Ag = A + (size_t)(row0 + srow) * K_ + scol;
    const u16* Bg = Bt + (size_t)(col0 + srow) * K_ + scol;
    char* AsBase = (char*)As + (size_t)(wave * 8) * (BK * 2);
    char* BsBase = (char*)Bs + (size_t)(wave * 8) * (BK * 2);

    for (int kt = 0; kt < K_ / BK; ++kt) {
        const int k0 = kt * BK;
#pragma unroll
        for (int i = 0; i < 4; ++i) {
            async_load16(Ag + (size_t)(i * 32) * K_ + k0,
                         AsBase + (size_t)(i * 32) * (BK * 2));
            async_load16(Bg + (size_t)(i * 32) * K_ + k0,
                         BsBase + (size_t)(i * 32) * (BK * 2));
        }
        __syncthreads();  // drains vmcnt -> LDS tiles complete

#pragma unroll
        for (int ks = 0; ks < 2; ++ks) {
            short8 af[4], bf[4];
#pragma unroll
            for (int mt = 0; mt < 4; ++mt) {
                const int r = wm * 64 + mt * 16 + (lane & 15);
                const int q = ks * 4 + (lane >> 4);       // 16B chunk index
                const int c = q ^ (r & 7);                // XOR de-swizzle
                af[mt] = *reinterpret_cast<const short8*>(
                    (const char*)As + (size_t)r * (BK * 2) + c * 16);
            }
#pragma unroll
            for (int nt = 0; nt < 4; ++nt) {
                const int r = wn * 64 + nt * 16 + (lane & 15);
                const int q = ks * 4 + (lane >> 4);
                const int c = q ^ (r & 7);
                bf[nt] = *reinterpret_cast<const short8*>(
                    (const char*)Bs + (size_t)r * (BK * 2) + c * 16);
            }
#pragma unroll
            for (int mt = 0; mt < 4; ++mt)
#pragma unroll
                for (int nt = 0; nt < 4; ++nt)
                    acc[mt][nt] = __builtin_amdgcn_mfma_f32_16x16x32_bf16(
                        af[mt], bf[nt], acc[mt][nt], 0, 0, 0);
        }
        __syncthreads();  // protect LDS from next iteration's staging
    }

    // epilogue: C/D layout col = lane&15, row = (lane>>4)*4 + reg
#pragma unroll
    for (int mt = 0; mt < 4; ++mt) {
#pragma unroll
        for (int nt = 0; nt < 4; ++nt) {
            const int r0 = row0 + wm * 64 + mt * 16 + (lane >> 4) * 4;
            const int c  = col0 + wn * 64 + nt * 16 + (lane & 15);
#pragma unroll
            for (int r = 0; r < 4; ++r)
                C[(size_t)(r0 + r) * N_ + c] = acc[mt][nt][r];
        }
    }
}

// ---------------------------------------------------------------------------
extern "C" void kernel_launch(void* const* d_in, const int* in_sizes, int n_in,
                              void* d_out, int out_size, void* d_ws, size_t ws_size,
                              hipStream_t stream) {
    const float* x      = (const float*)d_in[0];   // (S,B,H)
    const float* scale  = (const float*)d_in[1];   // (H,)
    const float* lnbias = (const float*)d_in[2];   // (H,)
    const float* weight = (const float*)d_in[3];   // (H,F)

    float* out    = (float*)d_out;                     // (S,B,F)
    float* ln_out = (float*)d_out + (size_t)M_ * N_;   // (S,B,H)

    // workspace: [A bf16: M_*K_ u16 = 64 MiB][Bt bf16: N_*K_ u16 = 2 MiB]
    u16* ln_bf16 = (u16*)d_ws;
    u16* bt      = (u16*)d_ws + (size_t)M_ * K_;

    transpose_cast_kernel<<<dim3(N_ / 32, K_ / 32), dim3(32, 8), 0, stream>>>(
        weight, bt);
    ln_kernel<<<LN_BLOCKS, 256, 0, stream>>>(x, scale, lnbias, ln_out, ln_bf16);
    gemm_bt_kernel<<<(M_ / BM) * (N_ / BN), 256, 0, stream>>>(ln_bf16, bt, out);
}